// Round 11
// baseline (422.678 us; speedup 1.0000x reference)
//
#include <hip/hip_runtime.h>

typedef __attribute__((ext_vector_type(8))) short s8v;
typedef __attribute__((ext_vector_type(4))) short s4v;
typedef __attribute__((ext_vector_type(4))) float f4v;
typedef __attribute__((ext_vector_type(4))) unsigned int u4v;

#define LOG2E 1.44269504088896340736f

__device__ __forceinline__ unsigned short f2bf(float f) {
    unsigned int x = __float_as_uint(f);
    return (unsigned short)((x + 0x7fffu + ((x >> 16) & 1u)) >> 16);
}
__device__ __forceinline__ s8v ld8(const unsigned short* p) {
    return *(const s8v*)p;
}

// async global->LDS, 16B per lane; LDS dest is wave-uniform base + lane*16
#define GLOAD_LDS(g, l) __builtin_amdgcn_global_load_lds(              \
    (const __attribute__((address_space(1))) void*)(const void*)(g),   \
    (__attribute__((address_space(3))) void*)(void*)(l), 16, 0, 0)

// ------- 4x W transpose + fp32->bf16 in one launch -------------------------
__global__ __launch_bounds__(256) void transpose_w4(
    const float* __restrict__ W0, const float* __restrict__ W1,
    const float* __restrict__ W2, const float* __restrict__ W3,
    unsigned short* __restrict__ T0, unsigned short* __restrict__ T1,
    unsigned short* __restrict__ T2, unsigned short* __restrict__ T3)
{
    __shared__ float tile[32][33];
    int z = blockIdx.z;
    const float* W = z == 0 ? W0 : z == 1 ? W1 : z == 2 ? W2 : W3;
    unsigned short* Wt = z == 0 ? T0 : z == 1 ? T1 : z == 2 ? T2 : T3;
    int tx = threadIdx.x, ty = threadIdx.y;
    int x = blockIdx.x * 32 + tx;
#pragma unroll
    for (int i = 0; i < 4; i++) {
        int y = blockIdx.y * 32 + ty + i * 8;
        tile[ty + i * 8][tx] = W[y * 1024 + x];
    }
    __syncthreads();
    int x2 = blockIdx.y * 32 + tx;
#pragma unroll
    for (int i = 0; i < 4; i++) {
        int y2 = blockIdx.x * 32 + ty + i * 8;
        Wt[y2 * 1024 + x2] = f2bf(tile[tx][ty + i * 8]);
    }
}

// ------- fused QKV GEMM, 256x256 / BK=64 / 4-phase counted schedule --------
// {q,k,v}[8192,1024]fp32 @ W^T + bias.  8 waves (2M x 4N), wave tile 128x64.
// 16 K-tiles of 64; LDS = A,B bf16 dbuf'd per tile (128 KB).  Per tile:
// 4 quadrant phases {ds_read; barrier; lgkm0; 16 MFMA; barrier}.  A(t+1)
// fp32->regs issued ph0, cvt_pk + swizzled ds_write at ph3 (T14); B(t+2)
// global_load_lds issued ph3; single vmcnt(4) per tile leaves B(t+2) in
// flight across the barrier (T4 - never drains mid-loop).  Chunk swizzle
// s ^= (row&7) on B source, A write, and all ds_reads (T2, rule #21).
// z=0: qw [b,h,l,d] * sscale. z=1: kw. z=2: vtw [b,h,d,l'] key-permuted.
#define LOADA(MH)                                                             \
    _Pragma("unroll") for (int m_ = 0; m_ < 4; m_++)                          \
    _Pragma("unroll") for (int k_ = 0; k_ < 2; k_++)                          \
        af[m_][k_] = *(const s8v*)(ab +                                       \
            (wr * 128 + (MH) * 64 + m_ * 16 + l15) * 128 +                    \
            ((k_ * 64 + quad * 16) ^ xsw));
#define LOADB(NH)                                                             \
    _Pragma("unroll") for (int n_ = 0; n_ < 2; n_++)                          \
    _Pragma("unroll") for (int k_ = 0; k_ < 2; k_++)                          \
        bfr[NH][n_][k_] = *(const s8v*)(bb +                                  \
            (wc * 64 + (NH) * 32 + n_ * 16 + l15) * 128 +                     \
            ((k_ * 64 + quad * 16) ^ xsw));
#define MFMA16(MH, NH)                                                        \
    _Pragma("unroll") for (int m_ = 0; m_ < 4; m_++)                          \
    _Pragma("unroll") for (int n_ = 0; n_ < 2; n_++)                          \
    _Pragma("unroll") for (int k_ = 0; k_ < 2; k_++)                          \
        acc[((MH) * 4 + m_) * 4 + (NH) * 2 + n_] =                            \
            __builtin_amdgcn_mfma_f32_16x16x32_bf16(af[m_][k_],               \
                bfr[NH][n_][k_], acc[((MH) * 4 + m_) * 4 + (NH) * 2 + n_],    \
                0, 0, 0);
#define LGKM0 asm volatile("s_waitcnt lgkmcnt(0)" ::: "memory")
#define SBAR  __builtin_amdgcn_s_barrier()
#define SCHB  __builtin_amdgcn_sched_barrier(0)

__global__ __launch_bounds__(512) void qkv8(
    const float* __restrict__ Aq, const float* __restrict__ Ak,
    const float* __restrict__ Avv,
    const unsigned short* __restrict__ BtQ, const unsigned short* __restrict__ BtK,
    const unsigned short* __restrict__ BtV,
    const float* __restrict__ bq, const float* __restrict__ bk,
    const float* __restrict__ bv,
    unsigned short* __restrict__ qo, unsigned short* __restrict__ ko,
    unsigned short* __restrict__ vo, float sscale)
{
    __shared__ __align__(16) unsigned short ldsA[2][256 * 64];
    __shared__ __align__(16) unsigned short ldsB[2][256 * 64];

    // grid 384 = 8 xcd * 12 (z,by)-panels * 4 bx  (bijective)
    int i = blockIdx.x;
    int c = i & 7, j = i >> 3;
    int p = j >> 2, bx = j & 3;
    int zy = c * 12 + p;                 // 0..95
    int z = zy >> 5, by = zy & 31;

    const float* A = z == 0 ? Aq : z == 1 ? Ak : Avv;
    const unsigned short* Bt = z == 0 ? BtQ : z == 1 ? BtK : BtV;
    const float* bias = z == 0 ? bq : z == 1 ? bk : bv;
    unsigned short* out = z == 0 ? qo : z == 1 ? ko : vo;
    float oscale = z == 0 ? sscale : 1.0f;

    int m0 = by * 256, n0 = bx * 256;
    int tid = threadIdx.x;
    int w = tid >> 6, lane = tid & 63;
    int quad = lane >> 4, l15 = lane & 15;
    int wr = w >> 2, wc = w & 3;         // 2M x 4N wave grid
    int xsw = (l15 & 7) << 4;

    // B staging: 4 chunks/thread (ch = jj*512 + tid); row=ch>>3, sub=ch&7;
    // linear LDS dest chunk ch; source chunk pre-swizzled sub^(row&7).
    const unsigned short* srcB[4];
#pragma unroll
    for (int jj = 0; jj < 4; jj++) {
        int ch = jj * 512 + tid;
        int row = ch >> 3, sub = ch & 7;
        srcB[jj] = Bt + (size_t)(n0 + row) * 1024 + (sub ^ (row & 7)) * 8;
    }
    // A reg-staging: row = tid>>1, half = tid&1 (32 fp32 each)
    int arow = tid >> 1, ahalf = tid & 1;
    const float* apA = A + (size_t)(m0 + arow) * 1024 + ahalf * 32;
    int wbyte[4];
#pragma unroll
    for (int q4 = 0; q4 < 4; q4++)
        wbyte[q4] = arow * 128 + (((ahalf * 4 + q4) * 16) ^ ((arow & 7) << 4));

    f4v acc[32];
#pragma unroll
    for (int a_ = 0; a_ < 32; a_++) { f4v zz = {0.f, 0.f, 0.f, 0.f}; acc[a_] = zz; }
    s8v af[4][2];
    s8v bfr[2][2][2];
    f4v areg[8];

    auto stageB = [&](int buf, int k0) {
#pragma unroll
        for (int jj = 0; jj < 4; jj++)
            GLOAD_LDS(srcB[jj] + k0, &ldsB[buf][jj * 4096 + w * 512]);
    };
    auto issueA = [&](int kt) {
        const float* an = apA + kt * 64;
#pragma unroll
        for (int jj = 0; jj < 8; jj++) areg[jj] = *(const f4v*)(an + jj * 4);
    };
    auto writeA = [&](int buf) {
        char* base = (char*)&ldsA[buf][0];
#pragma unroll
        for (int q4 = 0; q4 < 4; q4++) {
            unsigned int w0, w1, w2, w3;
            asm("v_cvt_pk_bf16_f32 %0, %1, %2" : "=v"(w0)
                : "v"(areg[2 * q4][0]), "v"(areg[2 * q4][1]));
            asm("v_cvt_pk_bf16_f32 %0, %1, %2" : "=v"(w1)
                : "v"(areg[2 * q4][2]), "v"(areg[2 * q4][3]));
            asm("v_cvt_pk_bf16_f32 %0, %1, %2" : "=v"(w2)
                : "v"(areg[2 * q4 + 1][0]), "v"(areg[2 * q4 + 1][1]));
            asm("v_cvt_pk_bf16_f32 %0, %1, %2" : "=v"(w3)
                : "v"(areg[2 * q4 + 1][2]), "v"(areg[2 * q4 + 1][3]));
            u4v wv; wv[0] = w0; wv[1] = w1; wv[2] = w2; wv[3] = w3;
            *(u4v*)(base + wbyte[q4]) = wv;
        }
    };

    // prologue: A(0) regs + B(0),B(1) staged; A(0) cvt+written to bufA0
    issueA(0);
    stageB(0, 0);
    stageB(1, 64);
    asm volatile("s_waitcnt vmcnt(8)" ::: "memory");   // A(0) landed
    SCHB;
    writeA(0);
    LGKM0;
    asm volatile("s_waitcnt vmcnt(4)" ::: "memory");   // B(0) landed, B(1) in flight
    SBAR;

    for (int t = 0; t < 16; t++) {
        const char* ab = (const char*)&ldsA[t & 1][0];
        const char* bb = (const char*)&ldsB[t & 1][0];
        // --- phase 0: quadrant (0,0); issue A(t+1) fp32 loads ---
        LOADA(0)
        LOADB(0)
        if (t < 15) issueA(t + 1);
        SBAR; LGKM0; SCHB;
        __builtin_amdgcn_s_setprio(1); MFMA16(0, 0); __builtin_amdgcn_s_setprio(0);
        SBAR;
        // --- phase 1: quadrant (0,1) ---
        LOADB(1)
        SBAR; LGKM0; SCHB;
        __builtin_amdgcn_s_setprio(1); MFMA16(0, 1); __builtin_amdgcn_s_setprio(0);
        SBAR;
        // --- phase 2: quadrant (1,0) ---
        LOADA(1)
        SBAR; LGKM0; SCHB;
        __builtin_amdgcn_s_setprio(1); MFMA16(1, 0); __builtin_amdgcn_s_setprio(0);
        SBAR;
        // --- phase 3: quadrant (1,1); stage B(t+2); cvt+write A(t+1) ---
        if (t < 14) stageB(t & 1, (t + 2) * 64);
        __builtin_amdgcn_s_setprio(1); MFMA16(1, 1); __builtin_amdgcn_s_setprio(0);
        if (t < 15) {
            if (t < 14) asm volatile("s_waitcnt vmcnt(4)" ::: "memory");
            else        asm volatile("s_waitcnt vmcnt(0)" ::: "memory");
            SCHB;
            writeA((t + 1) & 1);
            LGKM0;
        }
        SBAR;
    }

    // epilogue
#pragma unroll
    for (int mh = 0; mh < 2; mh++)
#pragma unroll
    for (int m = 0; m < 4; m++)
#pragma unroll
    for (int nh = 0; nh < 2; nh++)
#pragma unroll
    for (int n2 = 0; n2 < 2; n2++) {
        f4v a = acc[(mh * 4 + m) * 4 + nh * 2 + n2];
        int col = n0 + wc * 64 + nh * 32 + n2 * 16 + l15;
        float bvf = bias[col];
        int hh = col >> 6, d = col & 63;
#pragma unroll
        for (int r = 0; r < 4; r++) {
            int row = m0 + wr * 128 + mh * 64 + m * 16 + quad * 4 + r;
            float v = (a[r] + bvf) * oscale;
            int bb2 = row >> 11, l = row & 2047;
            if (z != 2) {
                out[(((size_t)bb2 * 16 + hh) * 2048 + l) * 64 + d] = f2bf(v);
            } else {
                int jj = l & 63;  // key -> storage slot permutation
                int s = ((jj & 0x0C) << 2) | ((jj & 0x02) << 2) |
                        ((jj & 0x30) >> 3) | (jj & 1);
                int lp = (l & ~63) | s;
                out[(((size_t)bb2 * 16 + hh) * 64 + d) * 2048 + lp] = f2bf(v);
            }
        }
    }
}

// ------- O-projection GEMM, counted-vmcnt triple-buffer (r8, verified) -----
__global__ __launch_bounds__(256) void gemm_ctd(
    const unsigned short* __restrict__ A,
    const unsigned short* __restrict__ Bt,
    const float* __restrict__ bias,
    float* __restrict__ out)
{
    __shared__ __align__(16) unsigned short ldsA[3][128 * 32];
    __shared__ __align__(16) unsigned short ldsB[3][128 * 32];

    int i = blockIdx.x;
    int c = i & 7, j = i >> 3;
    int bx = j & 7, by = c * 8 + (j >> 3);

    int tid = threadIdx.x;
    int w = tid >> 6, lane = tid & 63;
    int quad = lane >> 4, l15 = lane & 15;
    int wr = w >> 1, wc = w & 1;
    int m0 = by * 128, n0 = bx * 128;

    int r1 = tid >> 2, qp = tid & 3;
    int qs = (qp ^ (r1 & 3)) * 8;
    const unsigned short* ga1 = A  + (size_t)(m0 + r1) * 1024 + qs;
    const unsigned short* ga2 = A  + (size_t)(m0 + r1 + 64) * 1024 + qs;
    const unsigned short* gb1 = Bt + (size_t)(n0 + r1) * 1024 + qs;
    const unsigned short* gb2 = Bt + (size_t)(n0 + r1 + 64) * 1024 + qs;

    f4v acc[4][4];
#pragma unroll
    for (int m = 0; m < 4; m++)
#pragma unroll
        for (int n = 0; n < 4; n++) { f4v zz = {0.f, 0.f, 0.f, 0.f}; acc[m][n] = zz; }

    auto stage = [&](int buf, int k0) {
        GLOAD_LDS(ga1 + k0, &ldsA[buf][w * 512]);
        GLOAD_LDS(ga2 + k0, &ldsA[buf][2048 + w * 512]);
        GLOAD_LDS(gb1 + k0, &ldsB[buf][w * 512]);
        GLOAD_LDS(gb2 + k0, &ldsB[buf][2048 + w * 512]);
    };

    int xr = (l15 & 3) << 4;

    stage(0, 0);
    stage(1, 32);
    asm volatile("s_waitcnt vmcnt(4)" ::: "memory");
    asm volatile("s_barrier" ::: "memory");

    int buf = 0;
    for (int t = 0; t < 32; t++) {
        if (t < 30) {
            int nb = buf + 2; if (nb >= 3) nb -= 3;
            stage(nb, (t + 2) * 32);
        }
        const char* ab = (const char*)&ldsA[buf][0];
        const char* bb = (const char*)&ldsB[buf][0];
        s8v af[4], bfr[4];
#pragma unroll
        for (int m = 0; m < 4; m++)
            af[m] = *(const s8v*)(ab + (wr * 64 + m * 16 + l15) * 64 + ((quad * 16) ^ xr));
#pragma unroll
        for (int n = 0; n < 4; n++)
            bfr[n] = *(const s8v*)(bb + (wc * 64 + n * 16 + l15) * 64 + ((quad * 16) ^ xr));
        __builtin_amdgcn_s_setprio(1);
#pragma unroll
        for (int m = 0; m < 4; m++)
#pragma unroll
            for (int n = 0; n < 4; n++)
                acc[m][n] = __builtin_amdgcn_mfma_f32_16x16x32_bf16(af[m], bfr[n], acc[m][n], 0, 0, 0);
        __builtin_amdgcn_s_setprio(0);
        if (t < 31) {
            if (t < 30) asm volatile("s_waitcnt vmcnt(4)" ::: "memory");
            else        asm volatile("s_waitcnt vmcnt(0)" ::: "memory");
            asm volatile("s_barrier" ::: "memory");
            __builtin_amdgcn_sched_barrier(0);
        }
        buf++; if (buf >= 3) buf = 0;
    }

#pragma unroll
    for (int n = 0; n < 4; n++) {
        int col = n0 + wc * 64 + n * 16 + l15;
        float bvf = bias[col];
#pragma unroll
        for (int m = 0; m < 4; m++)
#pragma unroll
            for (int r2 = 0; r2 < 4; r2++) {
                int row = m0 + wr * 64 + m * 16 + quad * 4 + r2;
                out[(size_t)row * 1024 + col] = acc[m][n][r2] + bvf;
            }
    }
}

// ------- Flash attention (causal), swapped-QK^T, LDS-shared K/V ------------
// (unchanged from r9 — 89 us, verified)
__global__ __launch_bounds__(256) void attn_kernel(
    const unsigned short* __restrict__ Q,
    const unsigned short* __restrict__ K,
    const unsigned short* __restrict__ Vt,
    unsigned short* __restrict__ O)
{
    __shared__ __align__(16) unsigned short Kb[2][64 * 64];
    __shared__ __align__(16) unsigned short Vb[2][64 * 64];

    int tid = threadIdx.x;
    int w = tid >> 6, lane = tid & 63;
    int quad = lane >> 4, l15 = lane & 15;

    int bid = blockIdx.x;
    int swz = (bid & 7) * 128 + (bid >> 3);
    int xp = swz & 15;
    int h = (swz >> 4) & 15;
    int b = swz >> 8;
    int bh = b * 16 + h;

    int srow = tid >> 3;
    int soff = ((tid & 7) * 16) ^ ((srow & 7) << 4);
    const unsigned short* Kbase = K + (size_t)bh * 2048 * 64;
    const unsigned short* Vbase = Vt + (size_t)bh * 64 * 2048;

    auto stageK = [&](int buf, int kt) {
        const unsigned short* g1 = Kbase + (size_t)(kt * 64 + srow) * 64 + (soff >> 1);
        GLOAD_LDS(g1, &Kb[buf][w * 512]);
        GLOAD_LDS(g1 + (size_t)32 * 64, &Kb[buf][2048 + w * 512]);
    };
    auto stageV = [&](int buf, int kt) {
        const unsigned short* g1 = Vbase + (size_t)srow * 2048 + kt * 64 + (soff >> 1);
        GLOAD_LDS(g1, &Vb[buf][w * 512]);
        GLOAD_LDS(g1 + (size_t)32 * 2048, &Vb[buf][2048 + w * 512]);
    };

    int rswz = (l15 & 7) << 4;

#pragma unroll 1
    for (int half = 0; half < 2; half++) {
        int qt = half ? 31 - xp : xp;
        int m0 = qt * 64 + w * 16;

        const unsigned short* qb = Q + ((size_t)bh * 2048 + m0 + l15) * 64 + quad * 8;
        s8v aq0 = ld8(qb), aq1 = ld8(qb + 32);

        float mrun = -1e30f, lsum = 0.f;
        f4v oacc[4];
#pragma unroll
        for (int t = 0; t < 4; t++) { f4v z = {0.f, 0.f, 0.f, 0.f}; oacc[t] = z; }

        stageK(0, 0);
        stageV(0, 0);
        __syncthreads();

#pragma unroll 1
        for (int kt = 0; kt <= qt; kt++) {
            int buf = kt & 1;
            if (kt < qt) { stageK(buf ^ 1, kt + 1); stageV(buf ^ 1, kt + 1); }

            f4v sacc[4];
#pragma unroll
            for (int t = 0; t < 4; t++) { f4v z = {0.f, 0.f, 0.f, 0.f}; sacc[t] = z; }
            const char* kbp = (const char*)&Kb[buf][0];
#pragma unroll
            for (int t = 0; t < 4; t++) {
                int rb = (t * 16 + l15) * 128;
                s8v k0 = *(const s8v*)(kbp + rb + ((quad * 16) ^ rswz));
                s8v k1 = *(const s8v*)(kbp + rb + ((64 + quad * 16) ^ rswz));
                sacc[t] = __builtin_amdgcn_mfma_f32_16x16x32_bf16(k0, aq0, sacc[t], 0, 0, 0);
                sacc[t] = __builtin_amdgcn_mfma_f32_16x16x32_bf16(k1, aq1, sacc[t], 0, 0, 0);
            }

            if (kt == qt) {
                int qrow = w * 16 + l15;
#pragma unroll
                for (int t = 0; t < 4; t++)
#pragma unroll
                    for (int r = 0; r < 4; r++) {
                        int key = t * 16 + quad * 4 + r;
                        if (key > qrow) sacc[t][r] = -1e30f;
                    }
            }

            float tmax[4];
#pragma unroll
            for (int t = 0; t < 4; t++)
                tmax[t] = fmaxf(fmaxf(sacc[t][0], sacc[t][1]),
                                fmaxf(sacc[t][2], sacc[t][3]));
            float mx = fmaxf(fmaxf(tmax[0], tmax[1]), fmaxf(tmax[2], tmax[3]));
            mx = fmaxf(mx, __shfl_xor(mx, 16));
            mx = fmaxf(mx, __shfl_xor(mx, 32));

            if (__any(mx > mrun + 8.0f)) {
                float mnew = fmaxf(mrun, mx);
                float alpha = exp2f(mrun - mnew);
                lsum *= alpha;
#pragma unroll
                for (int r = 0; r < 4; r++) {
                    float ar = __shfl(alpha, quad * 4 + r);
#pragma unroll
                    for (int t2 = 0; t2 < 4; t2++) oacc[t2][r] *= ar;
                }
                mrun = mnew;
            }

            float ps[4];
#pragma unroll
            for (int t = 0; t < 4; t++) {
                float p0 = exp2f(sacc[t][0] - mrun);
                float p1 = exp2f(sacc[t][1] - mrun);
                float p2 = exp2f(sacc[t][2] - mrun);
                float p3 = exp2f(sacc[t][3] - mrun);
                sacc[t][0] = p0; sacc[t][1] = p1;
                sacc[t][2] = p2; sacc[t][3] = p3;
                ps[t] = (p0 + p1) + (p2 + p3);
            }
            lsum += (ps[0] + ps[1]) + (ps[2] + ps[3]);

            unsigned int pwv[4][2];
#pragma unroll
            for (int t = 0; t < 4; t++) {
                asm("v_cvt_pk_bf16_f32 %0, %1, %2"
                    : "=v"(pwv[t][0]) : "v"(sacc[t][0]), "v"(sacc[t][1]));
                asm("v_cvt_pk_bf16_f32 %0, %1, %2"
                    : "=v"(pwv[t][1]) : "v"(sacc[t][2]), "v"(sacc[t][3]));
            }

            const char* vbp = (const char*)&Vb[buf][0];
#pragma unroll
            for (int cc = 0; cc < 2; cc++) {
                u4v aw;
                aw[0] = pwv[0][cc]; aw[1] = pwv[1][cc];
                aw[2] = pwv[2][cc]; aw[3] = pwv[3][cc];
                s8v apf = __builtin_bit_cast(s8v, aw);
#pragma unroll
                for (int t2 = 0; t2 < 4; t2++) {
                    int rb = (t2 * 16 + l15) * 128;
                    s8v bvv = *(const s8v*)(vbp + rb + ((quad * 32 + cc * 16) ^ rswz));
                    oacc[t2] = __builtin_amdgcn_mfma_f32_16x16x32_bf16(apf, bvv, oacc[t2], 0, 0, 0);
                }
            }
            __syncthreads();
        }

        float ltot = lsum;
        ltot += __shfl_xor(ltot, 16);
        ltot += __shfl_xor(ltot, 32);
        float inv = 1.f / ltot;
#pragma unroll
        for (int r = 0; r < 4; r++) {
            float ir = __shfl(inv, quad * 4 + r);
            int l = m0 + quad * 4 + r;
#pragma unroll
            for (int t2 = 0; t2 < 4; t2++) {
                O[((size_t)b * 2048 + l) * 1024 + h * 64 + t2 * 16 + l15] = f2bf(oacc[t2][r] * ir);
            }
        }
    }
}

// ------- launch ------------------------------------------------------------
extern "C" void kernel_launch(void* const* d_in, const int* in_sizes, int n_in,
                              void* d_out, int out_size, void* d_ws, size_t ws_size,
                              hipStream_t stream)
{
    const float* queries = (const float*)d_in[0];
    const float* keys    = (const float*)d_in[1];
    const float* values  = (const float*)d_in[2];
    const float* Wq = (const float*)d_in[3];
    const float* bq = (const float*)d_in[4];
    const float* Wk = (const float*)d_in[5];
    const float* bk = (const float*)d_in[6];
    const float* Wv = (const float*)d_in[7];
    const float* bv = (const float*)d_in[8];
    const float* Wo = (const float*)d_in[9];
    const float* bo = (const float*)d_in[10];

    // ws (bf16 elems): 4x1M W^T + 3x8M Q/K/V^T + 8M ow = 72 MB
    unsigned short* ws = (unsigned short*)d_ws;
    const size_t M1 = 1u << 20, M8 = 8u << 20;
    unsigned short* WqT = ws;
    unsigned short* WkT = ws + 1 * M1;
    unsigned short* WvT = ws + 2 * M1;
    unsigned short* WoT = ws + 3 * M1;
    unsigned short* qw  = ws + 4 * M1;      // [B,H,L,64]
    unsigned short* kw  = qw + M8;          // [B,H,L,64]
    unsigned short* vtw = kw + M8;          // [B,H,64,L] (key-permuted)
    unsigned short* ow  = vtw + M8;         // [B*L,1024]

    const float sscale = 0.125f * LOG2E;

    dim3 tb(32, 8);
    transpose_w4<<<dim3(32, 32, 4), tb, 0, stream>>>(
        Wq, Wk, Wv, Wo, WqT, WkT, WvT, WoT);

    qkv8<<<dim3(384), 512, 0, stream>>>(
        queries, keys, values, WqT, WkT, WvT, bq, bk, bv,
        qw, kw, vtw, sscale);

    attn_kernel<<<dim3(1024), 256, 0, stream>>>(qw, kw, vtw, ow);

    gemm_ctd<<<dim3(512), 256, 0, stream>>>(ow, WoT, bo, (float*)d_out);
}